// Round 5
// baseline (218.052 us; speedup 1.0000x reference)
//
#include <hip/hip_runtime.h>

#define D_FEAT 128
#define SCAN_BS 1024

// ================= CSR-bucketing path (no fp32 atomics) =================
//
// ws layout (4-byte words), N = nodes, E = edges, nb = ceil(N/1024):
//   cnt    [0,   N)       int    in-degree histogram (zeroed)
//   deg    [N,  2N)       float  out-degree (mode 0 only, zeroed)
//   off    [2N, 3N+1)     int    exclusive prefix of cnt (off[N] = E)
//   cursor [3N+1,4N+1)    int    bucket fill cursors (init = off)
//   norm   [4N+1,5N+1)    float  deg^-1/2 (mode 0)
//   bsum   [5N+1, +nb)    int    per-block sums
//   boff   [.., +nb)      int    exclusive scan of bsum
//   perm   [.., +E)       int    edge ids bucketed by dst (4B scatter, not 8B)
//   hb     [.., +64N)     uint   bf16-packed h (2 feats/word)  [bf16 tier only]

__device__ __forceinline__ unsigned rne_bf16(float f) {
    unsigned u = __float_as_uint(f);
    return (u + 0x7FFFu + ((u >> 16) & 1u)) >> 16;   // round-to-nearest-even
}

// fused: bf16 convert (blocks [0, convBlocks)) + dst histogram (rest)
__global__ void prep_kernel(const float* __restrict__ h, uint4* __restrict__ hb, int nvec,
                            int convBlocks,
                            const int* __restrict__ src, const int* __restrict__ dst,
                            int* __restrict__ cnt, float* __restrict__ deg,
                            int E, const int* __restrict__ mode) {
    int b = blockIdx.x;
    if (b < convBlocks) {
        int i = b * 256 + threadIdx.x;
        if (i >= nvec) return;
        const float4* hp = (const float4*)h;
        float4 a = hp[2 * i], c = hp[2 * i + 1];
        uint4 r;
        r.x = (rne_bf16(a.y) << 16) | rne_bf16(a.x);
        r.y = (rne_bf16(a.w) << 16) | rne_bf16(a.z);
        r.z = (rne_bf16(c.y) << 16) | rne_bf16(c.x);
        r.w = (rne_bf16(c.w) << 16) | rne_bf16(c.z);
        hb[i] = r;
    } else {
        int e = (b - convBlocks) * 256 + threadIdx.x;
        if (e >= E) return;
        atomicAdd(&cnt[dst[e]], 1);
        if (*mode != 1) atomicAdd(&deg[src[e]], 1.0f);
    }
}

// Level 1: per-block exclusive scan of cnt -> off (block-local), block sums -> bsum
__global__ void block_scan_kernel(const int* __restrict__ cnt, int* __restrict__ off,
                                  int* __restrict__ bsum, int N) {
    __shared__ int sdata[SCAN_BS];
    int tid = threadIdx.x;
    int i = blockIdx.x * SCAN_BS + tid;
    int x = (i < N) ? cnt[i] : 0;
    sdata[tid] = x;
    __syncthreads();
    for (int ofs = 1; ofs < SCAN_BS; ofs <<= 1) {
        int v = (tid >= ofs) ? sdata[tid - ofs] : 0;
        __syncthreads();
        sdata[tid] += v;
        __syncthreads();
    }
    if (i < N) off[i] = sdata[tid] - x;          // block-local exclusive
    if (tid == SCAN_BS - 1) bsum[blockIdx.x] = sdata[tid];
}

// Level 2: scan the nb block sums
__global__ void scan_sums_kernel(const int* __restrict__ bsum, int* __restrict__ boff,
                                 int* __restrict__ offN, int nb) {
    if (nb <= 64) {
        int lane = threadIdx.x;                  // launched with 64 threads
        int x = (lane < nb) ? bsum[lane] : 0;
        int incl = x;
        #pragma unroll
        for (int ofs = 1; ofs < 64; ofs <<= 1) {
            int v = __shfl_up(incl, ofs, 64);
            if (lane >= ofs) incl += v;
        }
        if (lane < nb) boff[lane] = incl - x;
        if (lane == 63) *offN = incl;
    } else if (threadIdx.x == 0) {
        int acc = 0;
        for (int b = 0; b < nb; ++b) { boff[b] = acc; acc += bsum[b]; }
        *offN = acc;
    }
}

// Level 3: add block offsets, init cursors, compute norm (mode 0)
__global__ void finalize_kernel(int* __restrict__ off, int* __restrict__ cursor,
                                const int* __restrict__ boff, const float* __restrict__ deg,
                                float* __restrict__ norm, int N, const int* __restrict__ mode) {
    int i = blockIdx.x * blockDim.x + threadIdx.x;
    if (i >= N) return;
    int v = off[i] + boff[i / SCAN_BS];
    off[i] = v;
    cursor[i] = v;
    if (*mode != 1) norm[i] = rsqrtf(deg[i]);    // deg==0 -> inf, matches powf(0,-0.5)
}

// 4B scatter per edge (was 8B): only the edge id. src/w resolved at gather time.
__global__ void bucket_kernel(const int* __restrict__ dst, int* __restrict__ cursor,
                              int* __restrict__ perm, int E) {
    int e = blockIdx.x * blockDim.x + threadIdx.x;
    if (e >= E) return;
    int pos = atomicAdd(&cursor[dst[e]], 1);
    perm[pos] = e;
}

// 64-lane wave per node, 2 edges per iteration; lane owns 4 feats (uint2 bf16).
// halves accumulate alternate edges, combined by shfl_xor(32) at the end.
__global__ void gather64_bf16_kernel(const unsigned* __restrict__ hb, const int* __restrict__ off,
                                     const int* __restrict__ perm, const int* __restrict__ src,
                                     const float* __restrict__ w, const float* __restrict__ norm,
                                     float* __restrict__ out, int N, const int* __restrict__ mode) {
    long long gid = (long long)blockIdx.x * blockDim.x + threadIdx.x;
    int node = (int)(gid >> 6);
    if (node >= N) return;
    int lane = (int)(gid & 63);
    int half = lane >> 5;
    int fl   = lane & 31;
    int beg = off[node], end = off[node + 1];
    bool m1 = (*mode == 1);
    float a0 = 0.f, a1 = 0.f, a2 = 0.f, a3 = 0.f;
    for (int j = beg; j < end; j += 2) {
        int jj = j + half;
        bool vld = jj < end;
        int jc = vld ? jj : j;               // j itself is always < end here
        int e = perm[jc];
        int s = src[e];
        float sc = m1 ? w[e] : norm[s];
        if (!vld) sc = 0.f;
        uint2 hv = ((const uint2*)(hb + (long long)s * (D_FEAT / 2)))[fl];
        float f0 = __uint_as_float(hv.x << 16);
        float f1 = __uint_as_float(hv.x & 0xFFFF0000u);
        float f2 = __uint_as_float(hv.y << 16);
        float f3 = __uint_as_float(hv.y & 0xFFFF0000u);
        a0 += f0 * sc; a1 += f1 * sc; a2 += f2 * sc; a3 += f3 * sc;
    }
    a0 += __shfl_xor(a0, 32);
    a1 += __shfl_xor(a1, 32);
    a2 += __shfl_xor(a2, 32);
    a3 += __shfl_xor(a3, 32);
    if (half == 0) {
        float fin = m1 ? 1.0f : norm[node];
        float4 r; r.x = a0 * fin; r.y = a1 * fin; r.z = a2 * fin; r.w = a3 * fin;
        ((float4*)(out + (long long)node * D_FEAT))[fl] = r;
    }
}

// f32 tier (ws too small for hb): same structure, float4 row slices.
__global__ void gather64_f32_kernel(const float* __restrict__ h, const int* __restrict__ off,
                                    const int* __restrict__ perm, const int* __restrict__ src,
                                    const float* __restrict__ w, const float* __restrict__ norm,
                                    float* __restrict__ out, int N, const int* __restrict__ mode) {
    long long gid = (long long)blockIdx.x * blockDim.x + threadIdx.x;
    int node = (int)(gid >> 6);
    if (node >= N) return;
    int lane = (int)(gid & 63);
    int half = lane >> 5;
    int fl   = lane & 31;
    int beg = off[node], end = off[node + 1];
    bool m1 = (*mode == 1);
    float a0 = 0.f, a1 = 0.f, a2 = 0.f, a3 = 0.f;
    for (int j = beg; j < end; j += 2) {
        int jj = j + half;
        bool vld = jj < end;
        int jc = vld ? jj : j;
        int e = perm[jc];
        int s = src[e];
        float sc = m1 ? w[e] : norm[s];
        if (!vld) sc = 0.f;
        float4 v = ((const float4*)(h + (long long)s * D_FEAT))[fl];
        a0 += v.x * sc; a1 += v.y * sc; a2 += v.z * sc; a3 += v.w * sc;
    }
    a0 += __shfl_xor(a0, 32);
    a1 += __shfl_xor(a1, 32);
    a2 += __shfl_xor(a2, 32);
    a3 += __shfl_xor(a3, 32);
    if (half == 0) {
        float fin = m1 ? 1.0f : norm[node];
        float4 r; r.x = a0 * fin; r.y = a1 * fin; r.z = a2 * fin; r.w = a3 * fin;
        ((float4*)(out + (long long)node * D_FEAT))[fl] = r;
    }
}

// ================= fallback: atomic scatter =================

__global__ void fb_deg_kernel(const int* __restrict__ src, float* __restrict__ deg,
                              int E, const int* __restrict__ mode) {
    if (*mode == 1) return;
    int e = blockIdx.x * blockDim.x + threadIdx.x;
    if (e < E) atomicAdd(&deg[src[e]], 1.0f);
}
__global__ void fb_norm_kernel(const float* __restrict__ deg, float* __restrict__ norm,
                               int N, const int* __restrict__ mode) {
    if (*mode == 1) return;
    int i = blockIdx.x * blockDim.x + threadIdx.x;
    if (i < N) norm[i] = rsqrtf(deg[i]);
}
__global__ void fb_scatter_kernel(const float* __restrict__ h, const float* __restrict__ w,
                                  const int* __restrict__ src, const int* __restrict__ dst,
                                  const float* __restrict__ norm, float* __restrict__ out,
                                  int E, const int* __restrict__ mode) {
    long long gid = (long long)blockIdx.x * blockDim.x + threadIdx.x;
    int e = (int)(gid >> 5);
    int lane = (int)(gid & 31);
    if (e >= E) return;
    int s = src[e], d = dst[e];
    float scale = (*mode == 1) ? w[e] : norm[s];
    float4 v = ((const float4*)(h + (long long)s * D_FEAT))[lane];
    float* op = out + (long long)d * D_FEAT + lane * 4;
    atomicAdd(op + 0, v.x * scale);
    atomicAdd(op + 1, v.y * scale);
    atomicAdd(op + 2, v.z * scale);
    atomicAdd(op + 3, v.w * scale);
}
__global__ void fb_scale_kernel(float* __restrict__ out, const float* __restrict__ norm,
                                int N, const int* __restrict__ mode) {
    if (*mode == 1) return;
    int idx = blockIdx.x * blockDim.x + threadIdx.x;
    int total = N * (D_FEAT / 4);
    if (idx >= total) return;
    int node = idx / (D_FEAT / 4);
    float4* op = (float4*)out + idx;
    float4 v = *op;
    float nn = norm[node];
    v.x *= nn; v.y *= nn; v.z *= nn; v.w *= nn;
    *op = v;
}

extern "C" void kernel_launch(void* const* d_in, const int* in_sizes, int n_in,
                              void* d_out, int out_size, void* d_ws, size_t ws_size,
                              hipStream_t stream) {
    const float* h    = (const float*)d_in[0];
    const float* w    = (const float*)d_in[1];
    const int*   src  = (const int*)d_in[2];
    const int*   dst  = (const int*)d_in[3];
    const int*   mode = (const int*)d_in[4];

    int ND = in_sizes[0];
    int E  = in_sizes[1];
    int N  = ND / D_FEAT;
    int nb = (N + SCAN_BS - 1) / SCAN_BS;

    float* out = (float*)d_out;

    size_t base_words = (size_t)5 * N + 1 + 2 * (size_t)nb;  // cnt..boff
    size_t perm_off   = base_words;
    size_t hb_off     = (perm_off + (size_t)E + 3) & ~(size_t)3;  // 16B align
    size_t need_f32   = (perm_off + (size_t)E) * 4;
    size_t need_bf16  = (hb_off + (size_t)N * (D_FEAT / 2)) * 4;

    if (ws_size >= need_f32) {
        int*   cnt    = (int*)d_ws;
        float* deg    = (float*)(cnt + N);
        int*   off    = (int*)(deg + N);
        int*   cursor = off + N + 1;
        float* norm   = (float*)(cursor + N);
        int*   bsum   = (int*)(norm + N);
        int*   boff   = bsum + nb;
        int*   perm   = (int*)d_ws + perm_off;
        unsigned* hb  = (unsigned*)((int*)d_ws + hb_off);

        bool use_bf16 = (ws_size >= need_bf16);

        // zero cnt + deg (adjacent, 2N words)
        hipMemsetAsync(d_ws, 0, (size_t)2 * N * sizeof(int), stream);

        int nvec = use_bf16 ? (N * D_FEAT / 8) : 0;
        int convBlocks = use_bf16 ? ((nvec + 255) / 256) : 0;
        int histBlocks = (E + 255) / 256;
        prep_kernel<<<convBlocks + histBlocks, 256, 0, stream>>>(
            h, (uint4*)hb, nvec, convBlocks, src, dst, cnt, deg, E, mode);

        block_scan_kernel<<<nb, SCAN_BS, 0, stream>>>(cnt, off, bsum, N);
        scan_sums_kernel<<<1, 64, 0, stream>>>(bsum, boff, &off[N], nb);
        finalize_kernel<<<(N + 255) / 256, 256, 0, stream>>>(off, cursor, boff, deg,
                                                             norm, N, mode);
        bucket_kernel<<<(E + 255) / 256, 256, 0, stream>>>(dst, cursor, perm, E);

        long long gt = (long long)N * 64;
        int gblocks = (int)((gt + 255) / 256);
        if (use_bf16) {
            gather64_bf16_kernel<<<gblocks, 256, 0, stream>>>(hb, off, perm, src, w,
                                                              norm, out, N, mode);
        } else {
            gather64_f32_kernel<<<gblocks, 256, 0, stream>>>(h, off, perm, src, w,
                                                             norm, out, N, mode);
        }
    } else {
        // fallback: atomic scatter
        float* deg  = (float*)d_ws;
        float* norm = deg + N;
        hipMemsetAsync(d_out, 0, (size_t)out_size * sizeof(float), stream);
        hipMemsetAsync(d_ws, 0, (size_t)N * sizeof(float), stream);
        fb_deg_kernel<<<(E + 255) / 256, 256, 0, stream>>>(src, deg, E, mode);
        fb_norm_kernel<<<(N + 255) / 256, 256, 0, stream>>>(deg, norm, N, mode);
        long long tt = (long long)E * 32;
        fb_scatter_kernel<<<(int)((tt + 255) / 256), 256, 0, stream>>>(h, w, src, dst,
                                                                       norm, out, E, mode);
        int st = N * (D_FEAT / 4);
        fb_scale_kernel<<<(st + 255) / 256, 256, 0, stream>>>(out, norm, N, mode);
    }
}

// Round 8
// 166.842 us; speedup vs baseline: 1.3069x; 1.3069x over previous
//
#include <hip/hip_runtime.h>

#define D_FEAT 128

// ================= fixed-capacity bucketing (no hist, no scan) =================
//
// ws layout (4-byte words), N = nodes, E = edges, CAP = per-node bucket capacity:
//   cursor [0,  N)      int    per-node fill count (zeroed by memset)
//   deg    [N, 2N)      float  out-degree (mode 0 only, zeroed)
//   ovfcnt [2N]         int    overflow-list count (zeroed)
//   ovf    [2N+1, +E)   int    overflow edge ids (edges beyond CAP; ~never used)
//   epack  [aligned, N*CAP uint2]  {src, w_bits} per node bucket
//
// CAP is chosen from ws_size on the host (>=32 in practice). P(in-degree > CAP)
// is astronomically small for random dst, but the overflow path is fully correct:
// a gather wave whose node overflowed scans the (tiny) ovf list for its edges.

// one pass over edges: count degree, place edge record into its dst bucket
__global__ void bucket_direct_kernel(const int* __restrict__ src, const int* __restrict__ dst,
                                     const float* __restrict__ w,
                                     int* __restrict__ cursor, float* __restrict__ deg,
                                     int* __restrict__ ovfcnt, int* __restrict__ ovf,
                                     uint2* __restrict__ epack, int cap,
                                     int E, const int* __restrict__ mode) {
    int e = blockIdx.x * blockDim.x + threadIdx.x;
    if (e >= E) return;
    bool m1 = (*mode == 1);
    int d = dst[e];
    int s = src[e];
    if (!m1) atomicAdd(&deg[s], 1.0f);           // out-degree (mode 0 normalization)
    int pos = atomicAdd(&cursor[d], 1);
    if (pos < cap) {
        float sc = m1 ? w[e] : 0.0f;             // mode 0 scale resolved at gather (needs full deg)
        epack[(size_t)d * cap + pos] = make_uint2((unsigned)s, __float_as_uint(sc));
    } else {
        int o = atomicAdd(ovfcnt, 1);
        ovf[o] = e;
    }
}

// 32 lanes per dst node; each lane owns one float4 slice of D=128.
__global__ void gather_cap_kernel(const float* __restrict__ h,
                                  const int* __restrict__ cursor, const float* __restrict__ deg,
                                  const uint2* __restrict__ epack, int cap,
                                  const int* __restrict__ ovfcnt, const int* __restrict__ ovf,
                                  const int* __restrict__ src, const int* __restrict__ dst,
                                  const float* __restrict__ w,
                                  float* __restrict__ out, int N, const int* __restrict__ mode) {
    long long gid = (long long)blockIdx.x * blockDim.x + threadIdx.x;
    int node = (int)(gid >> 5);
    int lane = (int)(gid & 31);
    if (node >= N) return;
    bool m1 = (*mode == 1);
    int cnt = cursor[node];
    int inb = cnt < cap ? cnt : cap;
    const uint2* row = epack + (size_t)node * cap;
    float a0 = 0.f, a1 = 0.f, a2 = 0.f, a3 = 0.f;
    for (int j = 0; j < inb; ++j) {
        uint2 m = row[j];                        // broadcast: all 32 lanes same address
        int s = (int)m.x;
        float sc = m1 ? __uint_as_float(m.y) : rsqrtf(deg[s]);
        float4 v = ((const float4*)(h + (long long)s * D_FEAT))[lane];
        a0 += v.x * sc; a1 += v.y * sc; a2 += v.z * sc; a3 += v.w * sc;
    }
    if (cnt > cap) {
        // overflow slow path (correct for any input; never taken for random dst):
        // this node's extra edges are in the global ovf list — scan it.
        int total = *ovfcnt;
        for (int k = 0; k < total; ++k) {
            int e = ovf[k];
            if (dst[e] == node) {
                int s = src[e];
                float sc = m1 ? w[e] : rsqrtf(deg[s]);
                float4 v = ((const float4*)(h + (long long)s * D_FEAT))[lane];
                a0 += v.x * sc; a1 += v.y * sc; a2 += v.z * sc; a3 += v.w * sc;
            }
        }
    }
    float fin = m1 ? 1.0f : rsqrtf(deg[node]);   // deg==0 -> inf; 0*inf=nan matches ref
    float4 r; r.x = a0 * fin; r.y = a1 * fin; r.z = a2 * fin; r.w = a3 * fin;
    ((float4*)(out + (long long)node * D_FEAT))[lane] = r;
}

// ================= ultra-fallback: atomic scatter (ws too small; unused in practice) =================

__global__ void fb_deg_kernel(const int* __restrict__ src, float* __restrict__ deg,
                              int E, const int* __restrict__ mode) {
    if (*mode == 1) return;
    int e = blockIdx.x * blockDim.x + threadIdx.x;
    if (e < E) atomicAdd(&deg[src[e]], 1.0f);
}
__global__ void fb_norm_kernel(const float* __restrict__ deg, float* __restrict__ norm,
                               int N, const int* __restrict__ mode) {
    if (*mode == 1) return;
    int i = blockIdx.x * blockDim.x + threadIdx.x;
    if (i < N) norm[i] = rsqrtf(deg[i]);
}
__global__ void fb_scatter_kernel(const float* __restrict__ h, const float* __restrict__ w,
                                  const int* __restrict__ src, const int* __restrict__ dst,
                                  const float* __restrict__ norm, float* __restrict__ out,
                                  int E, const int* __restrict__ mode) {
    long long gid = (long long)blockIdx.x * blockDim.x + threadIdx.x;
    int e = (int)(gid >> 5);
    int lane = (int)(gid & 31);
    if (e >= E) return;
    int s = src[e], d = dst[e];
    float scale = (*mode == 1) ? w[e] : norm[s];
    float4 v = ((const float4*)(h + (long long)s * D_FEAT))[lane];
    float* op = out + (long long)d * D_FEAT + lane * 4;
    atomicAdd(op + 0, v.x * scale);
    atomicAdd(op + 1, v.y * scale);
    atomicAdd(op + 2, v.z * scale);
    atomicAdd(op + 3, v.w * scale);
}
__global__ void fb_scale_kernel(float* __restrict__ out, const float* __restrict__ norm,
                                int N, const int* __restrict__ mode) {
    if (*mode == 1) return;
    int idx = blockIdx.x * blockDim.x + threadIdx.x;
    int total = N * (D_FEAT / 4);
    if (idx >= total) return;
    int node = idx / (D_FEAT / 4);
    float4* op = (float4*)out + idx;
    float4 v = *op;
    float nn = norm[node];
    v.x *= nn; v.y *= nn; v.z *= nn; v.w *= nn;
    *op = v;
}

// ================= host =================

extern "C" void kernel_launch(void* const* d_in, const int* in_sizes, int n_in,
                              void* d_out, int out_size, void* d_ws, size_t ws_size,
                              hipStream_t stream) {
    const float* h    = (const float*)d_in[0];
    const float* w    = (const float*)d_in[1];
    const int*   src  = (const int*)d_in[2];
    const int*   dst  = (const int*)d_in[3];
    const int*   mode = (const int*)d_in[4];

    int ND = in_sizes[0];
    int E  = in_sizes[1];
    int N  = ND / D_FEAT;

    float* out = (float*)d_out;

    // layout (words): cursor[N] | deg[N] | ovfcnt[1] | ovf[E] | (align 8B) | epack[N*cap]
    size_t fixed_words = 2 * (size_t)N + 1 + (size_t)E;
    size_t epack_off   = (fixed_words + 1) & ~(size_t)1;
    size_t ws_words    = ws_size / 4;

    int cap = 0;
    if (ws_words > epack_off)
        cap = (int)((ws_words - epack_off) / (2 * (size_t)N));   // uint2 per slot
    if (cap > 64) cap = 64;

    if (cap >= 8) {
        int*   cursor = (int*)d_ws;
        float* deg    = (float*)(cursor + N);
        int*   ovfcnt = (int*)(deg + N);
        int*   ovf    = ovfcnt + 1;
        uint2* epack  = (uint2*)((int*)d_ws + epack_off);

        // zero cursor + deg + ovfcnt (contiguous 2N+1 words)
        hipMemsetAsync(d_ws, 0, (2 * (size_t)N + 1) * sizeof(int), stream);

        bucket_direct_kernel<<<(E + 255) / 256, 256, 0, stream>>>(
            src, dst, w, cursor, deg, ovfcnt, ovf, epack, cap, E, mode);

        long long gt = (long long)N * 32;
        gather_cap_kernel<<<(int)((gt + 255) / 256), 256, 0, stream>>>(
            h, cursor, deg, epack, cap, ovfcnt, ovf, src, dst, w, out, N, mode);
    } else {
        // fallback: atomic scatter
        float* deg  = (float*)d_ws;
        float* norm = deg + N;
        hipMemsetAsync(d_out, 0, (size_t)out_size * sizeof(float), stream);
        hipMemsetAsync(d_ws, 0, (size_t)N * sizeof(float), stream);
        fb_deg_kernel<<<(E + 255) / 256, 256, 0, stream>>>(src, deg, E, mode);
        fb_norm_kernel<<<(N + 255) / 256, 256, 0, stream>>>(deg, norm, N, mode);
        long long tt = (long long)E * 32;
        fb_scatter_kernel<<<(int)((tt + 255) / 256), 256, 0, stream>>>(h, w, src, dst,
                                                                       norm, out, E, mode);
        int st = N * (D_FEAT / 4);
        fb_scale_kernel<<<(st + 255) / 256, 256, 0, stream>>>(out, norm, N, mode);
    }
}